// Round 1
// baseline (141.463 us; speedup 1.0000x reference)
//
#include <hip/hip_runtime.h>

namespace {

constexpr int Hh = 512;    // input H
constexpr int Ww = 512;    // input W
constexpr int OH = 1024;   // output H
constexpr int OW = 1024;   // output W

// One thread computes one aligned 2x2 output block for one (b, c_out).
// Needs the 3x3 input neighborhood per band (4 bands).
__global__ __launch_bounds__(256) void ihaar(
    const float* __restrict__ x,
    const float* __restrict__ f0,
    const float* __restrict__ f1,
    const float* __restrict__ f2,
    const float* __restrict__ f3,
    float* __restrict__ out)
{
  const int xb = blockIdx.x * 256 + threadIdx.x;  // output block col 0..511
  const int y  = blockIdx.y;                      // output block row 0..511
  const int bc = blockIdx.z;                      // b*3 + c, 0..47
  const int b  = bc / 3;
  const int c  = bc - 3 * b;

  // 2x2 filters, row-major: (f00, f01, f10, f11)
  const float4 F[4] = { *(const float4*)f0, *(const float4*)f1,
                        *(const float4*)f2, *(const float4*)f3 };

  // Upsample row weights for up-rows {2y-1 (A), 2y (B), 2y+1 (C)}
  // expressed over input rows {u0=y-1, y, u2=y+1} (clamped, zero-weighted at edges).
  float wA0, wA1, wB0, wB1, wC1, wC2;
  if (y > 0) { wA0 = 0.75f; wA1 = 0.25f; wB0 = 0.25f; wB1 = 0.75f; }
  else       { wA0 = 0.0f;  wA1 = 0.0f;  wB0 = 0.0f;  wB1 = 1.0f; }
  if (y < Hh - 1) { wC1 = 0.75f; wC2 = 0.25f; } else { wC1 = 1.0f; wC2 = 0.0f; }

  float vA0, vA1, vB0, vB1, vC1, vC2;
  if (xb > 0) { vA0 = 0.75f; vA1 = 0.25f; vB0 = 0.25f; vB1 = 0.75f; }
  else        { vA0 = 0.0f;  vA1 = 0.0f;  vB0 = 0.0f;  vB1 = 1.0f; }
  if (xb < Ww - 1) { vC1 = 0.75f; vC2 = 0.25f; } else { vC1 = 1.0f; vC2 = 0.0f; }

  const int u0 = (y > 0) ? y - 1 : 0;
  const int u2 = (y < Hh - 1) ? y + 1 : y;
  const int l0 = (xb > 0) ? xb - 1 : 0;
  const int l2 = (xb < Ww - 1) ? xb + 1 : xb;

  float o00 = 0.f, o01 = 0.f, o10 = 0.f, o11 = 0.f;

#pragma unroll
  for (int g = 0; g < 4; ++g) {
    const float* Xp = x + (size_t)(b * 12 + g * 3 + c) * (Hh * Ww);
    const float* r0 = Xp + u0 * Ww;
    const float* r1 = Xp + y  * Ww;
    const float* r2 = Xp + u2 * Ww;

    const float X00 = r0[l0], X01 = r0[xb], X02 = r0[l2];
    const float X10 = r1[l0], X11 = r1[xb], X12 = r1[l2];
    const float X20 = r2[l0], X21 = r2[xb], X22 = r2[l2];

    // row-combine -> values of up-rows A/B/C at the 3 loaded input cols
    const float rA0 = wA0 * X00 + wA1 * X10;
    const float rA1 = wA0 * X01 + wA1 * X11;
    const float rA2 = wA0 * X02 + wA1 * X12;
    const float rB0 = wB0 * X00 + wB1 * X10;
    const float rB1 = wB0 * X01 + wB1 * X11;
    const float rB2 = wB0 * X02 + wB1 * X12;
    const float rC0 = wC1 * X10 + wC2 * X20;
    const float rC1 = wC1 * X11 + wC2 * X21;
    const float rC2 = wC1 * X12 + wC2 * X22;

    // col-combine -> up values at up-cols {2x-1 (A), 2x (B), 2x+1 (C)}
    const float uAA = vA0 * rA0 + vA1 * rA1;
    const float uAB = vB0 * rA0 + vB1 * rA1;
    const float uAC = vC1 * rA1 + vC2 * rA2;
    const float uBA = vA0 * rB0 + vA1 * rB1;
    const float uBB = vB0 * rB0 + vB1 * rB1;
    const float uBC = vC1 * rB1 + vC2 * rB2;
    const float uCA = vA0 * rC0 + vA1 * rC1;
    const float uCB = vB0 * rC0 + vB1 * rC1;
    const float uCC = vC1 * rC1 + vC2 * rC2;

    // out[i][j] = f00*up[i-1][j-1] + f01*up[i-1][j] + f10*up[i][j-1] + f11*up[i][j]
    const float f00 = F[g].x, f01 = F[g].y, f10 = F[g].z, f11 = F[g].w;
    o00 += f00 * uAA + f01 * uAB + f10 * uBA + f11 * uBB;
    o01 += f00 * uAB + f01 * uAC + f10 * uBB + f11 * uBC;
    o10 += f00 * uBA + f01 * uBB + f10 * uCA + f11 * uCB;
    o11 += f00 * uBB + f01 * uBC + f10 * uCB + f11 * uCC;
  }

  float* op = out + ((size_t)bc * OH + 2 * y) * OW + 2 * xb;
  *(float2*)op        = make_float2(o00, o01);
  *(float2*)(op + OW) = make_float2(o10, o11);
}

} // namespace

extern "C" void kernel_launch(void* const* d_in, const int* in_sizes, int n_in,
                              void* d_out, int out_size, void* d_ws, size_t ws_size,
                              hipStream_t stream) {
  const float* x   = (const float*)d_in[0];
  const float* fll = (const float*)d_in[1];
  const float* flh = (const float*)d_in[2];
  const float* fhl = (const float*)d_in[3];
  const float* fhh = (const float*)d_in[4];
  float* out = (float*)d_out;

  dim3 grid(Ww / 256, Hh, 16 * 3);  // (2, 512, 48)
  ihaar<<<grid, 256, 0, stream>>>(x, fll, flh, fhl, fhh, out);
}